// Round 5
// baseline (599.097 us; speedup 1.0000x reference)
//
#include <hip/hip_runtime.h>
#include <stdint.h>

// HungarianMatcher on MI355X — round 5.
// R4 was latency-bound: 210MB/155us = 1.35 TB/s. Little's law needs ~22KB/CU
// in flight for 6.3 TB/s; serial load->wait->compute gave ~4KB. Fix: explicit
// 2-deep register double-buffer in the k-loop (fine-grained vmcnt, AITER-style).
// Hungarian: JV greedy row-reduction init (exact; duals feasible + compl.
// slackness => same unique optimum) so only ~5 rows need Dijkstra.

#define BATCH 8
#define NQ    100
#define NT    32
#define HWP   65536      // 256*256
#define NCLS  81
#define BIGV  1.0e6
#define MPAD  112        // 7*16
#define MTILES 7
#define KSPLIT 16
#define KC (HWP / KSPLIT)   // 4096 px per block
#define KW (KC / 4)         // 1024 px per wave
#define NITER (KW / 64)     // 16 k-iters of 64 px

typedef __attribute__((ext_vector_type(8))) short short8;
typedef __attribute__((ext_vector_type(4))) float f32x4;

__device__ inline unsigned short f2bf(float f) {   // RNE fp32->bf16
    uint32_t u = __builtin_bit_cast(uint32_t, f);
    u += 0x7fffu + ((u >> 16) & 1u);
    return (unsigned short)(u >> 16);
}

// -------------------------------------------------------------------------
__global__ __launch_bounds__(256) void pack_kernel(const float* __restrict__ tmask,
                                                   uint32_t* __restrict__ packed,
                                                   int* __restrict__ tm_counts) {
    int idx = blockIdx.x * 256 + threadIdx.x;
    int b = idx >> 16;
    int p = idx & 65535;
    int y = p >> 8, x = p & 255;
    const float* base = tmask + (size_t)b * NT * 262144 + (size_t)(2 * y) * 512 + (2 * x);
    uint32_t w = 0;
#pragma unroll
    for (int t = 0; t < NT; ++t) {
        float v = base[(size_t)t * 262144];
        w |= (v > 0.5f ? 1u : 0u) << t;
    }
    packed[idx] = w;
    int lane = threadIdx.x & 63;
    int mycnt = 0;
#pragma unroll
    for (int t = 0; t < NT; ++t) {
        unsigned long long m = __ballot((w >> t) & 1u);
        if (lane == t) mycnt = __popcll(m);
    }
    if (lane < NT) atomicAdd(&tm_counts[b * NT + lane], mycnt);
}

// -------------------------------------------------------------------------
// accd: [2][BATCH][MPAD][32] fp32 (dot_pm, dot_sig); accs: [2][BATCH][MPAD]
__global__ __launch_bounds__(256) void mfma_kernel(const float* __restrict__ pmask,
                                                   const uint32_t* __restrict__ packed,
                                                   float* __restrict__ accd,
                                                   float* __restrict__ accs) {
    const int kblk = blockIdx.x;
    const int mt   = blockIdx.y;
    const int b    = blockIdx.z;
    const int tid  = threadIdx.x;
    const int wv   = tid >> 6, lane = tid & 63;
    const int m0   = mt * 16;
    const int q    = lane >> 4;    // 0..3  (k-quad)
    const int r    = lane & 15;    // 0..15 (A row / B target)

    __shared__ float Cred[8][16][32];

    int mrow = m0 + r; if (mrow > NQ - 1) mrow = NQ - 1;   // pad rows dup row 99
    const float* Arow = pmask + (size_t)b * NQ * HWP + (size_t)mrow * HWP;
    const uint32_t* pkb = packed + (size_t)b * HWP;
    const int kbase0 = kblk * KC + wv * KW;

    f32x4 Cpm0 = {0,0,0,0}, Cpm1 = {0,0,0,0}, Csg0 = {0,0,0,0}, Csg1 = {0,0,0,0};
    float rsp = 0.f, rsg = 0.f;

    float4 vaA[4], vaB[4];
    uint4  wbA[4], wbB[4];

    auto loadF = [&](int ki, float4* va, uint4* wb) {
        const int kb = kbase0 + ki * 64;
        va[0] = *(const float4*)(Arow + kb + q * 8);
        va[1] = *(const float4*)(Arow + kb + q * 8 + 4);
        va[2] = *(const float4*)(Arow + kb + 32 + q * 8);
        va[3] = *(const float4*)(Arow + kb + 32 + q * 8 + 4);
        wb[0] = *(const uint4*)(pkb + kb + q * 8);
        wb[1] = *(const uint4*)(pkb + kb + q * 8 + 4);
        wb[2] = *(const uint4*)(pkb + kb + 32 + q * 8);
        wb[3] = *(const uint4*)(pkb + kb + 32 + q * 8 + 4);
    };

    auto compute = [&](const float4* va, const uint4* wb) {
        short8 a0, a1, g0, g1;
        auto cvt4 = [&](const float4& v, short8& af, short8& gf, int base) {
#pragma unroll
            for (int e = 0; e < 4; ++e) {
                float pv = (&v.x)[e];
                float ax = fabsf(pv);
                float en = __expf(-ax);
                float inv = __builtin_amdgcn_rcpf(1.0f + en);
                float sig = (pv >= 0.f) ? inv : en * inv;
                float sp  = fmaxf(pv, 0.f) + __logf(1.0f + en);
                rsp += sp; rsg += sig;
                af[base + e] = (short)f2bf(pv);
                gf[base + e] = (short)f2bf(sig);
            }
        };
        cvt4(va[0], a0, g0, 0); cvt4(va[1], a0, g0, 4);
        cvt4(va[2], a1, g1, 0); cvt4(va[3], a1, g1, 4);

        short8 b00, b01, b10, b11;
        const unsigned short ONE = 0x3F80;
#pragma unroll
        for (int j = 0; j < 4; ++j) {
            uint32_t s;
            s = (&wb[0].x)[j] >> r;
            b00[j]     = (short)((s & 1u)         ? ONE : 0);
            b10[j]     = (short)(((s >> 16) & 1u) ? ONE : 0);
            s = (&wb[1].x)[j] >> r;
            b00[4 + j] = (short)((s & 1u)         ? ONE : 0);
            b10[4 + j] = (short)(((s >> 16) & 1u) ? ONE : 0);
            s = (&wb[2].x)[j] >> r;
            b01[j]     = (short)((s & 1u)         ? ONE : 0);
            b11[j]     = (short)(((s >> 16) & 1u) ? ONE : 0);
            s = (&wb[3].x)[j] >> r;
            b01[4 + j] = (short)((s & 1u)         ? ONE : 0);
            b11[4 + j] = (short)(((s >> 16) & 1u) ? ONE : 0);
        }

        Cpm0 = __builtin_amdgcn_mfma_f32_16x16x32_bf16(a0, b00, Cpm0, 0, 0, 0);
        Cpm0 = __builtin_amdgcn_mfma_f32_16x16x32_bf16(a1, b01, Cpm0, 0, 0, 0);
        Cpm1 = __builtin_amdgcn_mfma_f32_16x16x32_bf16(a0, b10, Cpm1, 0, 0, 0);
        Cpm1 = __builtin_amdgcn_mfma_f32_16x16x32_bf16(a1, b11, Cpm1, 0, 0, 0);
        Csg0 = __builtin_amdgcn_mfma_f32_16x16x32_bf16(g0, b00, Csg0, 0, 0, 0);
        Csg0 = __builtin_amdgcn_mfma_f32_16x16x32_bf16(g1, b01, Csg0, 0, 0, 0);
        Csg1 = __builtin_amdgcn_mfma_f32_16x16x32_bf16(g0, b10, Csg1, 0, 0, 0);
        Csg1 = __builtin_amdgcn_mfma_f32_16x16x32_bf16(g1, b11, Csg1, 0, 0, 0);
    };

    // software pipeline, depth 2: next iter's 8 loads are in flight while
    // computing the current iter (fine-grained vmcnt instead of vmcnt(0)).
    loadF(0, vaA, wbA);
    for (int ki = 0; ki < NITER; ki += 2) {
        loadF(ki + 1, vaB, wbB);
        compute(vaA, wbA);
        if (ki + 2 < NITER) loadF(ki + 2, vaA, wbA);
        compute(vaB, wbB);
    }

    // row sums: reduce across the 4 k-quads (lane bits 4,5)
    rsp += __shfl_xor(rsp, 16, 64);
    rsp += __shfl_xor(rsp, 32, 64);
    rsg += __shfl_xor(rsg, 16, 64);
    rsg += __shfl_xor(rsg, 32, 64);
    if (q == 0 && m0 + r < NQ) {
        atomicAdd(&accs[(size_t)b * MPAD + m0 + r], rsp);
        atomicAdd(&accs[(size_t)(BATCH + b) * MPAD + m0 + r], rsg);
    }

    // C/D layout: col = lane&15 (target), row = (lane>>4)*4 + e (query)
#pragma unroll
    for (int e = 0; e < 4; ++e) {
        const int m = q * 4 + e;
        Cred[wv * 2 + 0][m][r]      = Cpm0[e];
        Cred[wv * 2 + 0][m][16 + r] = Cpm1[e];
        Cred[wv * 2 + 1][m][r]      = Csg0[e];
        Cred[wv * 2 + 1][m][16 + r] = Csg1[e];
    }
    __syncthreads();
    for (int idx = tid; idx < 1024; idx += 256) {
        const int type = idx >> 9, rem = idx & 511, m = rem >> 5, n = rem & 31;
        float s = Cred[0 + type][m][n] + Cred[2 + type][m][n]
                + Cred[4 + type][m][n] + Cred[6 + type][m][n];
        const int gm = m0 + m;
        if (gm < NQ)
            atomicAdd(&accd[(size_t)(type * BATCH + b) * MPAD * 32 + (size_t)gm * 32 + n], s);
    }
}

// -------------------------------------------------------------------------
// Finalize cost matrix + exact JV Hungarian with greedy row-reduction init.
__global__ __launch_bounds__(64) void hungarian_kernel(const float* __restrict__ logits,
                                                       const int* __restrict__ labels,
                                                       const float* __restrict__ accd,
                                                       const float* __restrict__ accs,
                                                       const int* __restrict__ tm_counts,
                                                       int* __restrict__ out) {
    const int b = blockIdx.x;
    const int lane = threadIdx.x;

    __shared__ double Ct[NT][NQ];
    __shared__ double u[NT + 1];
    __shared__ float smx[NQ], ssm[NQ];
    __shared__ float tcs[NT];
    __shared__ int lab[NT];
    __shared__ unsigned char rowdone[NT + 1];

    if (lane < NT) { tcs[lane] = (float)tm_counts[b * NT + lane]; lab[lane] = labels[b * NT + lane]; }
    for (int n = lane; n < NQ; n += 64) {
        const float* lg = logits + (size_t)(b * NQ + n) * NCLS;
        float mx = -1e30f;
        for (int c = 0; c < NCLS; ++c) mx = fmaxf(mx, lg[c]);
        float s = 0.f;
        for (int c = 0; c < NCLS; ++c) s += __expf(lg[c] - mx);
        smx[n] = mx; ssm[n] = s;
    }
    if (lane <= NT) u[lane] = 0.0;
    __syncthreads();
    for (int idx = lane; idx < NQ * NT; idx += 64) {
        const int t2 = idx & 31, q2 = idx >> 5;
        float dpm = accd[(size_t)b * MPAD * 32 + q2 * 32 + t2];
        float dsg = accd[(size_t)(BATCH + b) * MPAD * 32 + q2 * 32 + t2];
        float ssp = accs[(size_t)b * MPAD + q2];
        float ssg = accs[(size_t)(BATCH + b) * MPAD + q2];
        float lg = logits[(size_t)(b * NQ + q2) * NCLS + lab[t2]];
        float prob = __expf(lg - smx[q2]) / ssm[q2];
        float c = -prob + (ssp - dpm) * (1.0f / (float)HWP)
                + 1.0f - (2.0f * dsg + 1.0f) / (ssg + tcs[t2] + 1.0f);
        if (isnan(c)) c = (float)BIGV;
        else if (isinf(c)) c = (c > 0.f) ? (float)BIGV : -(float)BIGV;
        Ct[t2][q2] = (double)c;
    }
    __syncthreads();

    const int c0 = lane + 1;
    const bool valid1 = (lane < NQ - 64);
    const int c1 = lane + 65;
    const int cidx1 = valid1 ? (lane + 64) : 0;

    double v0 = 0.0, v1 = 0.0;
    int p0 = 0, p1 = 0;

    // ---- greedy row-reduction init: u[i] = rowmin; assign if argmin col free.
    // Exact JV init: duals feasible (C-u-v >= 0), assigned pairs have reduced
    // cost 0 => shortest-augmenting-path on the remaining rows yields the
    // (unique) optimal assignment.
    for (int i = 1; i <= NT; ++i) {
        double bv = Ct[i - 1][lane]; int bj = c0;
        if (valid1) { double t = Ct[i - 1][cidx1]; if (t < bv) { bv = t; bj = c1; } }
#pragma unroll
        for (int s = 32; s > 0; s >>= 1) {
            double ov = __shfl_down(bv, s, 64);
            int    oj = __shfl_down(bj, s, 64);
            if (ov < bv || (ov == bv && oj < bj)) { bv = ov; bj = oj; }
        }
        double rmin = __shfl(bv, 0, 64);
        int jmin = __shfl(bj, 0, 64);
        int src = (jmin - 1) & 63, slot = (jmin - 1) >> 6;
        int pa = __shfl(p0, src, 64), pb = __shfl(p1, src, 64);
        int pj = slot ? pb : pa;
        if (lane == 0) { u[i] = rmin; rowdone[i] = (pj == 0) ? 1 : 0; }
        if (pj == 0) {
            if (c0 == jmin) p0 = i;
            if (valid1 && c1 == jmin) p1 = i;
        }
    }
    __syncthreads();
    double u_reg = (lane <= NT) ? u[lane] : 0.0;

    for (int i = 1; i <= NT; ++i) {
        if (rowdone[i]) continue;               // wave-uniform (LDS broadcast)
        double minv0 = 1e300, minv1 = 1e300;
        int way0 = 0, way1 = 0;
        bool used0 = false, used1 = !valid1;
        double du0 = 0.0, du1 = 0.0, dtot = 0.0;
        int j0 = 0, i0 = i;
        int jfin = 0;

        for (int guard = 0; guard < 160; ++guard) {
            double u_i0 = __shfl(u_reg, i0, 64);
            double cur0 = Ct[i0 - 1][lane] - u_i0 - v0;
            if (!used0 && cur0 < minv0) { minv0 = cur0; way0 = j0; }
            double cur1 = Ct[i0 - 1][cidx1] - u_i0 - v1;
            if (!used1 && cur1 < minv1) { minv1 = cur1; way1 = j0; }
            double bv = 1e301; int bj = 1 << 20;
            if (!used0) { bv = minv0; bj = c0; }
            if (!used1 && minv1 < bv) { bv = minv1; bj = c1; }
#pragma unroll
            for (int s = 32; s > 0; s >>= 1) {
                double ov = __shfl_down(bv, s, 64);
                int    oj = __shfl_down(bj, s, 64);
                if (ov < bv || (ov == bv && oj < bj)) { bv = ov; bj = oj; }
            }
            double delta = __shfl(bv, 0, 64);
            int j1 = __shfl(bj, 0, 64);
            dtot += delta;
            if (used0) { v0 -= delta; du0 += delta; } else { minv0 -= delta; }
            if (valid1) {
                if (used1) { v1 -= delta; du1 += delta; } else { minv1 -= delta; }
            }
            if (c0 == j1) used0 = true;
            if (valid1 && c1 == j1) used1 = true;
            int src = (j1 - 1) & 63, slot = (j1 - 1) >> 6;
            int pa = __shfl(p0, src, 64), pb = __shfl(p1, src, 64);
            int pj1 = slot ? pb : pa;
            if (pj1 == 0) { jfin = j1; break; }
            j0 = j1; i0 = pj1;
        }

        // deferred u updates (distinct rows across used cols -> race-free)
        if (used0 && p0 != 0) u[p0] += du0;
        if (valid1 && used1 && p1 != 0) u[p1] += du1;
        if (lane == 0) u[i] += dtot;

        int jj = jfin;
        for (int guard = 0; guard < 160 && jj != 0; ++guard) {
            int src = (jj - 1) & 63, slot = (jj - 1) >> 6;
            int wa = __shfl(way0, src, 64), wb = __shfl(way1, src, 64);
            int jprev = slot ? wb : wa;
            int pnew;
            if (jprev == 0) pnew = i;
            else {
                int s2 = (jprev - 1) & 63, sl2 = (jprev - 1) >> 6;
                int pa = __shfl(p0, s2, 64), pb = __shfl(p1, s2, 64);
                pnew = sl2 ? pb : pa;
            }
            if (c0 == jj) p0 = pnew;
            if (valid1 && c1 == jj) p1 = pnew;
            jj = jprev;
        }
        __syncthreads();
        u_reg = (lane <= NT) ? u[lane] : 0.0;   // refresh mirror once per row
    }

    unsigned long long m0 = __ballot(p0 != 0);
    unsigned long long m1 = __ballot(valid1 && p1 != 0);
    int base = b * NT;
    if (p0 != 0) {
        int rank = __popcll(m0 & ((1ull << lane) - 1ull));
        out[base + rank] = c0 - 1;
        out[BATCH * NT + base + rank] = p0 - 1;
    }
    if (valid1 && p1 != 0) {
        int rank = __popcll(m0) + __popcll(m1 & ((1ull << lane) - 1ull));
        out[base + rank] = c1 - 1;
        out[BATCH * NT + base + rank] = p1 - 1;
    }
}

// -------------------------------------------------------------------------
extern "C" void kernel_launch(void* const* d_in, const int* in_sizes, int n_in,
                              void* d_out, int out_size, void* d_ws, size_t ws_size,
                              hipStream_t stream) {
    const float* logits = (const float*)d_in[0];   // [8,100,81]
    const float* pmasks = (const float*)d_in[1];   // [8,100,256,256]
    const float* tmasks = (const float*)d_in[2];   // [8,32,512,512]
    const int*   labels = (const int*)d_in[3];     // [8,32]

    uint8_t* ws = (uint8_t*)d_ws;
    uint32_t* packed = (uint32_t*)ws;                       // 2 MiB
    uint8_t* zbase = ws + (size_t)BATCH * HWP * 4;
    int* tm_counts = (int*)zbase;                           // 1 KiB
    float* accd = (float*)(zbase + 1024);                   // 229376 B
    float* accs = (float*)(zbase + 1024 + 229376);          // 7168 B
    const size_t ztotal = 1024 + 229376 + 7168;

    int* out = (int*)d_out;   // int32: src [8,32] then tgt [8,32]

    hipMemsetAsync(zbase, 0, ztotal, stream);
    pack_kernel<<<BATCH * HWP / 256, 256, 0, stream>>>(tmasks, packed, tm_counts);
    mfma_kernel<<<dim3(KSPLIT, MTILES, BATCH), 256, 0, stream>>>(pmasks, packed, accd, accs);
    hungarian_kernel<<<BATCH, 64, 0, stream>>>(logits, labels, accd, accs, tm_counts, out);
}